// Round 3
// baseline (5829.550 us; speedup 1.0000x reference)
//
#include <hip/hip_runtime.h>
#include <hip/hip_fp16.h>
#include <math.h>

#define Bn 64
#define Tn 128
#define TCn 512
#define CEn 64
#define CHn 256
#define TAGSn 50
#define DWPn 640   // word-LSTM input dim padded 612 -> 640

__device__ __forceinline__ float sigf(float x){ return 1.0f/(1.0f+expf(-x)); }

__device__ __forceinline__ unsigned h2u(__half2 h){ union{__half2 h; unsigned u;} v; v.h=h; return v.u; }
__device__ __forceinline__ __half2 u2h(unsigned u){ union{__half2 h; unsigned u;} v; v.u=u; return v.h; }
__device__ __forceinline__ __half2 f2h2(float a, float b){
  __half2 r; r.x = __float2half_rn(a); r.y = __float2half_rn(b); return r;
}

// ---------------------------------------------------------------------------
// CW[d][c][u*4+k] = b_d[k*256+u] + sum_e ceW[c][e]*Wih_d[k*256+u][e]
__global__ void k_prep_cw(const float* __restrict__ ceW,
                          const float* __restrict__ Wf, const float* __restrict__ bf,
                          const float* __restrict__ Wb, const float* __restrict__ bb,
                          float* __restrict__ CWf, float* __restrict__ CWb){
  const int c = blockIdx.x, u = threadIdx.x;
  const float* Wih  = blockIdx.y ? Wb : Wf;
  const float* bias = blockIdx.y ? bb : bf;
  float*       CW   = blockIdx.y ? CWb : CWf;
  __shared__ float ce[CEn];
  if (u < CEn) ce[u] = ceW[c*CEn + u];
  __syncthreads();
  float a[4];
  #pragma unroll
  for (int k=0;k<4;k++){
    const float* wr = Wih + (size_t)(k*CHn+u)*CEn;
    float s = bias[k*CHn+u];
    #pragma unroll 4
    for (int e=0;e<CEn;e++) s += ce[e]*wr[e];
    a[k]=s;
  }
  ((float4*)CW)[c*CHn+u] = make_float4(a[0],a[1],a[2],a[3]);
}

// packed fp16 Whh: WH[e][u] = { half2(Wi,Wf), half2(Wg,Wo) } ; grid (256,4) x 256
__global__ void k_prep_wt(const float* __restrict__ W0, const float* __restrict__ W1,
                          const float* __restrict__ W2, const float* __restrict__ W3,
                          uint2* __restrict__ T0, uint2* __restrict__ T1,
                          uint2* __restrict__ T2, uint2* __restrict__ T3){
  const int e = blockIdx.x, u = threadIdx.x, w = blockIdx.y;
  const float* Wh = (w==0)?W0:(w==1)?W1:(w==2)?W2:W3;
  uint2*       Tt = (w==0)?T0:(w==1)?T1:(w==2)?T2:T3;
  const float a = Wh[(size_t)(0*CHn+u)*CHn + e];
  const float b = Wh[(size_t)(1*CHn+u)*CHn + e];
  const float c = Wh[(size_t)(2*CHn+u)*CHn + e];
  const float d = Wh[(size_t)(3*CHn+u)*CHn + e];
  uint2 v; v.x = h2u(f2h2(a,b)); v.y = h2u(f2h2(c,d));
  Tt[(size_t)e*CHn+u] = v;
}

// pad word Wih (1024,612) -> (1024,640)
__global__ void k_pad(const float* __restrict__ Wf, const float* __restrict__ Wb,
                      float* __restrict__ Pf, float* __restrict__ Pb){
  const int j = blockIdx.x;
  const float* Win  = blockIdx.y ? Wb : Wf;
  float*       Wout = blockIdx.y ? Pb : Pf;
  for (int col=threadIdx.x; col<DWPn; col+=256)
    Wout[(size_t)j*DWPn+col] = (col<612) ? Win[(size_t)j*612+col] : 0.f;
}

// pad emW (50,512)->(64,512), emb (50)->(64)
__global__ void k_pad_em(const float* __restrict__ emW, const float* __restrict__ emb,
                         float* __restrict__ Wp, float* __restrict__ bp){
  const int j = blockIdx.x;
  for (int col=threadIdx.x; col<512; col+=256)
    Wp[(size_t)j*512+col] = (j<TAGSn) ? emW[(size_t)j*512+col] : 0.f;
  if (threadIdx.x==0) bp[j] = (j<TAGSn) ? emb[j] : 0.f;
}

// stable-compaction ranks from cmakers only; grid (64,2), 64 threads (1 wave)
__global__ void k_prep_pos(const float* __restrict__ cmf, const float* __restrict__ cmb,
                           int* __restrict__ pf, int* __restrict__ pb){
  const float* cm = blockIdx.y ? cmb : cmf;
  int* pos        = blockIdx.y ? pb : pf;
  const int n = blockIdx.x, lane = threadIdx.x;
  int base = 0;
  for (int c=0;c<TCn/64;c++){
    int t = c*64 + lane;
    bool m = cm[n*TCn+t] != 0.f;
    unsigned long long bal = __ballot(m);
    int before = __popcll(bal & ((1ULL<<lane)-1ULL));
    int r = base + before;
    pos[n*TCn+t] = (m && r < Tn) ? r : -1;
    base += __popcll(bal);
  }
}

// ---------------------------------------------------------------------------
// char LSTM: 64 blocks (2 dirs x 32 pairs, R=2 rows), 1024 threads:
// u = unit (0..255), q = e-quarter (0..3, 64 e's each). Gate phase on q<2.
#define CLOADW(W,c) { _Pragma("unroll") for(int j=0;j<8;j++) \
    (W)[j] = WH[(size_t)((e0+(c)*8+j)*CHn)+u]; }
#define CLOADH(H,c) { const unsigned* b_ = hpar + e0 + (c)*8; \
  (H)[0]=*(const uint4*)(b_);     (H)[1]=*(const uint4*)(b_+4); \
  (H)[2]=*(const uint4*)(b_+264); (H)[3]=*(const uint4*)(b_+268); }
#define CCOMP(W,H) { _Pragma("unroll") for(int j=0;j<8;j++){ const int s_=j>>2; \
  const __half2 wif_=u2h((W)[j].x), wgo_=u2h((W)[j].y); \
  const __half2 h0_=u2h(((const unsigned*)(H))[j]); \
  const __half2 h1_=u2h(((const unsigned*)(H))[8+j]); \
  aIF[0][s_]=__hfma2(wif_,h0_,aIF[0][s_]); aGO[0][s_]=__hfma2(wgo_,h0_,aGO[0][s_]); \
  aIF[1][s_]=__hfma2(wif_,h1_,aIF[1][s_]); aGO[1][s_]=__hfma2(wgo_,h1_,aGO[1][s_]); } }

__global__ __launch_bounds__(1024, 4)
void k_char_lstm(const int* __restrict__ cmf, const int* __restrict__ cmb,
                 const float* __restrict__ CWf, const float* __restrict__ CWb,
                 const uint2* __restrict__ WHf, const uint2* __restrict__ WHb,
                 const int* __restrict__ posf, const int* __restrict__ posb,
                 float* __restrict__ sub){
  const int dir = blockIdx.x >> 5, pr = blockIdx.x & 31;
  const int n0 = pr*2;
  const int u = threadIdx.x & 255, q = threadIdx.x >> 8;
  const int*    cm  = dir ? cmb : cmf;
  const float4* CW  = (const float4*)(dir ? CWb : CWf);
  const uint2*  WH  = dir ? WHb : WHf;
  const int*    pos = dir ? posb : posf;
  const int dofs = dir ? CHn : 0;
  const int e0 = q*64;
  __align__(16) __shared__ unsigned hb2[2][2][264];
  __shared__ uint2 zredh[4][2][256];     // packed fp16 partials (i,f),(g,o)
  if (q==0){ hb2[0][0][u]=0u; hb2[0][1][u]=0u; }
  float cst = 0.f;                       // cell state: valid in q<2, row q
  int par = 0;
  __syncthreads();
  uint2 wA[8], wB[8]; uint4 hA[4], hB[4];
  CLOADW(wA,0)
  for (int t=0;t<TCn;t++){
    float4 zin = make_float4(0.f,0.f,0.f,0.f); int p = -1;
    if (q<2){
      const int ci = cm[(n0+q)*TCn + t];
      zin = CW[(size_t)ci*CHn + u];
      p = pos[(n0+q)*TCn + t];
    }
    const unsigned* hpar = &hb2[par][0][0];
    __half2 aIF[2][2], aGO[2][2];
    const __half2 hz = f2h2(0.f,0.f);
    aIF[0][0]=hz; aIF[0][1]=hz; aIF[1][0]=hz; aIF[1][1]=hz;
    aGO[0][0]=hz; aGO[0][1]=hz; aGO[1][0]=hz; aGO[1][1]=hz;
    CLOADH(hA,0)
    #pragma unroll
    for (int c=0;c<8;c+=2){
      CLOADW(wB,c+1) CLOADH(hB,c+1)
      CCOMP(wA,hA)
      if (c<6){ CLOADW(wA,c+2) CLOADH(hA,c+2) }
      else    { CLOADW(wA,0) }             // prefetch next step's chunk 0
      CCOMP(wB,hB)
    }
    zredh[q][0][u] = make_uint2(h2u(__hadd2(aIF[0][0],aIF[0][1])),
                                h2u(__hadd2(aGO[0][0],aGO[0][1])));
    zredh[q][1][u] = make_uint2(h2u(__hadd2(aIF[1][0],aIF[1][1])),
                                h2u(__hadd2(aGO[1][0],aGO[1][1])));
    __syncthreads();
    if (q<2){
      float zi=zin.x, zf=zin.y, zg=zin.z, zo=zin.w;
      #pragma unroll
      for (int qq=0;qq<4;qq++){
        uint2 v = zredh[qq][q][u];
        __half2 hif = u2h(v.x), hgo = u2h(v.y);
        zi += __low2float(hif); zf += __high2float(hif);
        zg += __low2float(hgo); zo += __high2float(hgo);
      }
      cst = sigf(zf)*cst + sigf(zi)*tanhf(zg);
      const float hn = sigf(zo)*tanhf(cst);
      hb2[par^1][q][u] = h2u(f2h2(hn,hn));
      if (p>=0) sub[(size_t)((n0+q)*Tn+p)*512 + dofs + u] = hn;
    }
    __syncthreads();
    par ^= 1;
  }
}

// ---------------------------------------------------------------------------
// word LSTM: scans over B=64 steps, batch T=128. 64 blocks (2 dirs x 32, R=4),
// 1024 threads: u = unit, q = e-quarter; gate phase: quarter q owns row q.
#define WLOADW(W,c) { _Pragma("unroll") for(int j=0;j<4;j++) \
    (W)[j] = WH[(size_t)((e0+(c)*4+j)*CHn)+u]; }
#define WLOADH(H,c) { const unsigned* b_ = hpar + e0 + (c)*4; \
  _Pragma("unroll") for(int r_=0;r_<4;r_++) (H)[r_]=*(const uint4*)(b_+r_*264); }
#define WCOMP(W,H) { _Pragma("unroll") for(int j=0;j<4;j++){ \
  const __half2 wif_=u2h((W)[j].x), wgo_=u2h((W)[j].y); \
  _Pragma("unroll") for(int r_=0;r_<4;r_++){ \
    const __half2 hh_=u2h(((const unsigned*)(H))[r_*4+j]); \
    aIF[r_]=__hfma2(wif_,hh_,aIF[r_]); aGO[r_]=__hfma2(wgo_,hh_,aGO[r_]); } } }

__global__ __launch_bounds__(1024, 4)
void k_word_lstm(const float* __restrict__ wXf, const float* __restrict__ wXb,
                 const uint2* __restrict__ WHf, const uint2* __restrict__ WHb,
                 float* __restrict__ hout){
  const int dir = blockIdx.x >> 5, qq5 = blockIdx.x & 31;
  const int t0 = qq5*4;
  const int u = threadIdx.x & 255, q = threadIdx.x >> 8;
  const float* wX = dir ? wXb : wXf;
  const uint2* WH = dir ? WHb : WHf;
  const int e0 = q*64;
  __align__(16) __shared__ unsigned hb2[2][4][264];
  __shared__ uint2 zredh[4][4][256];
  if (q==0){
    #pragma unroll
    for (int r=0;r<4;r++) hb2[0][r][u]=0u;
  }
  float cst = 0.f;                        // cell state for (row q, unit u)
  int par = 0;
  __syncthreads();
  uint2 wA[4], wB[4]; uint4 hA[4], hB[4];
  WLOADW(wA,0)
  for (int s=0;s<64;s++){
    const int n = dir ? (63-s) : s;
    const float* xr = wX + (size_t)(n*Tn + t0 + q)*1024 + u;
    float4 zin = make_float4(xr[0], xr[256], xr[512], xr[768]);
    const unsigned* hpar = &hb2[par][0][0];
    __half2 aIF[4], aGO[4];
    const __half2 hz = f2h2(0.f,0.f);
    #pragma unroll
    for (int r=0;r<4;r++){ aIF[r]=hz; aGO[r]=hz; }
    WLOADH(hA,0)
    #pragma unroll
    for (int c=0;c<16;c+=2){
      WLOADW(wB,c+1) WLOADH(hB,c+1)
      WCOMP(wA,hA)
      if (c<14){ WLOADW(wA,c+2) WLOADH(hA,c+2) }
      else     { WLOADW(wA,0) }
      WCOMP(wB,hB)
    }
    #pragma unroll
    for (int r=0;r<4;r++)
      zredh[q][r][u] = make_uint2(h2u(aIF[r]), h2u(aGO[r]));
    __syncthreads();
    {
      float zi=zin.x, zf=zin.y, zg=zin.z, zo=zin.w;
      #pragma unroll
      for (int qq=0;qq<4;qq++){
        uint2 v = zredh[qq][q][u];
        __half2 hif = u2h(v.x), hgo = u2h(v.y);
        zi += __low2float(hif); zf += __high2float(hif);
        zg += __low2float(hgo); zo += __high2float(hgo);
      }
      cst = sigf(zf)*cst + sigf(zi)*tanhf(zg);
      const float hn = sigf(zo)*tanhf(cst);
      hb2[par^1][q][u] = h2u(f2h2(hn,hn));
      hout[(size_t)(n*Tn + t0 + q)*512 + dir*CHn + u] = hn;
    }
    __syncthreads();
    par ^= 1;
  }
}

// ---------------------------------------------------------------------------
// generic fp32 GEMM: C[m][n] = bias[n] + sum_k A[m][k]*W[n][k]
__global__ __launch_bounds__(256)
void k_gemm(const float* __restrict__ A, int lda, int K, int ldw,
            const float* __restrict__ W0, const float* __restrict__ W1,
            const float* __restrict__ b0, const float* __restrict__ b1,
            float* __restrict__ C0, float* __restrict__ C1, int ldc){
  const float* W    = blockIdx.z ? W1 : W0;
  const float* bias = blockIdx.z ? b1 : b0;
  float*       C    = blockIdx.z ? C1 : C0;
  const int m0 = blockIdx.x*128, n0 = blockIdx.y*64;
  __shared__ float As[32][132];
  __shared__ float Bs[32][68];
  const int tid = threadIdx.x;
  float acc[8][4];
  #pragma unroll
  for (int i=0;i<8;i++){
    #pragma unroll
    for (int j=0;j<4;j++) acc[i][j]=0.f;
  }
  const int tm = tid & 15, tn = tid >> 4;
  for (int kc=0; kc<K; kc+=32){
    #pragma unroll
    for (int it=0; it<4; it++){
      int fl = tid + it*256; int r = fl>>3; int kq = fl&7;
      float4 v = *(const float4*)(A + (size_t)(m0+r)*lda + kc + kq*4);
      As[kq*4+0][r]=v.x; As[kq*4+1][r]=v.y; As[kq*4+2][r]=v.z; As[kq*4+3][r]=v.w;
    }
    #pragma unroll
    for (int it=0; it<2; it++){
      int fl = tid + it*256; int r = fl>>3; int kq = fl&7;
      float4 v = *(const float4*)(W + (size_t)(n0+r)*ldw + kc + kq*4);
      Bs[kq*4+0][r]=v.x; Bs[kq*4+1][r]=v.y; Bs[kq*4+2][r]=v.z; Bs[kq*4+3][r]=v.w;
    }
    __syncthreads();
    #pragma unroll
    for (int k=0;k<32;k++){
      float a[8], b[4];
      *(float4*)(a)   = *(const float4*)(&As[k][tm*8]);
      *(float4*)(a+4) = *(const float4*)(&As[k][tm*8+4]);
      *(float4*)(b)   = *(const float4*)(&Bs[k][tn*4]);
      #pragma unroll
      for (int i=0;i<8;i++){
        #pragma unroll
        for (int j=0;j<4;j++) acc[i][j] += a[i]*b[j];
      }
    }
    __syncthreads();
  }
  float4 bv = *(const float4*)(bias + n0 + tn*4);
  #pragma unroll
  for (int i=0;i<8;i++){
    float4 o = make_float4(acc[i][0]+bv.x, acc[i][1]+bv.y, acc[i][2]+bv.z, acc[i][3]+bv.w);
    *(float4*)(C + (size_t)(m0+tm*8+i)*ldc + n0 + tn*4) = o;
  }
}

// highway elementwise: sub = g*relu(zt) + (1-g)*sub
__global__ __launch_bounds__(256)
void k_hwelt(const float* __restrict__ hwz, float* __restrict__ sub){
  const int idx = blockIdx.x*256 + threadIdx.x;
  const int m = idx >> 7, j4 = idx & 127;
  float4 s  = ((const float4*)sub)[idx];
  float4 zt = ((const float4*)hwz)[(size_t)m*256 + j4];
  float4 zg = ((const float4*)hwz)[(size_t)m*256 + 128 + j4];
  float4 o;
  { float g=sigf(zg.x), tr=fmaxf(zt.x,0.f); o.x = g*tr + (1.f-g)*s.x; }
  { float g=sigf(zg.y), tr=fmaxf(zt.y,0.f); o.y = g*tr + (1.f-g)*s.y; }
  { float g=sigf(zg.z), tr=fmaxf(zt.z,0.f); o.z = g*tr + (1.f-g)*s.z; }
  { float g=sigf(zg.w), tr=fmaxf(zt.w,0.f); o.w = g*tr + (1.f-g)*s.w; }
  ((float4*)sub)[idx] = o;
}

// assemble padded word input
__global__ void k_wasm(const int* __restrict__ wmap, const float* __restrict__ weW,
                       const float* __restrict__ sub, float* __restrict__ w){
  const int m = blockIdx.x;
  const int wi = wmap[m];
  for (int col=threadIdx.x; col<DWPn; col+=256){
    float v = 0.f;
    if (col < 100)      v = weW[(size_t)wi*100 + col];
    else if (col < 612) v = sub[(size_t)m*512 + (col-100)];
    w[(size_t)m*DWPn + col] = v;
  }
}

// crf[m][a][b] = em[m][b] + trans[a][b] ; em ld=64
__global__ __launch_bounds__(256)
void k_crf(const float* __restrict__ em, const float* __restrict__ trans,
           float* __restrict__ out){
  const int m = blockIdx.x;
  __shared__ float er[TAGSn];
  if (threadIdx.x < TAGSn) er[threadIdx.x] = em[(size_t)m*64 + threadIdx.x];
  __syncthreads();
  float* o = out + (size_t)m*2500;
  for (int r=threadIdx.x; r<2500; r+=256)
    o[r] = er[r % TAGSn] + trans[r];
}

// int tail outputs as floats
__global__ void k_tail(const int* __restrict__ tm, const int* __restrict__ ln,
                       const int* __restrict__ tc, float* __restrict__ out){
  const int i = blockIdx.x*256 + threadIdx.x;
  if (i < 8192)       out[i] = (float)tm[i];
  else if (i < 8256)  out[i] = (float)ln[i-8192];
  else if (i < 16448) out[i] = (float)tc[i-8256];
}

// ---------------------------------------------------------------------------
extern "C" void kernel_launch(void* const* d_in, const int* in_sizes, int n_in,
                              void* d_out, int out_size, void* d_ws, size_t ws_size,
                              hipStream_t stream){
  (void)in_sizes; (void)n_in; (void)out_size; (void)ws_size;
  const int*   wmap   = (const int*)d_in[0];
  const int*   cmapsf = (const int*)d_in[1];
  const int*   cmapsb = (const int*)d_in[2];
  const float* cmakf  = (const float*)d_in[3];
  const float* cmakb  = (const float*)d_in[4];
  const int*   tmaps  = (const int*)d_in[5];
  const int*   tmapc  = (const int*)d_in[6];
  const int*   lengths= (const int*)d_in[7];
  const float* ceW    = (const float*)d_in[8];
  const float* fcWih  = (const float*)d_in[9];
  const float* fcWhh  = (const float*)d_in[10];
  const float* fcb    = (const float*)d_in[11];
  const float* bcWih  = (const float*)d_in[12];
  const float* bcWhh  = (const float*)d_in[13];
  const float* bcb    = (const float*)d_in[14];
  const float* weW    = (const float*)d_in[15];
  const float* wfWih  = (const float*)d_in[16];
  const float* wfWhh  = (const float*)d_in[17];
  const float* wfb    = (const float*)d_in[18];
  const float* wbWih  = (const float*)d_in[19];
  const float* wbWhh  = (const float*)d_in[20];
  const float* wbb    = (const float*)d_in[21];
  const float* hwWt   = (const float*)d_in[22];
  const float* hwbt   = (const float*)d_in[23];
  const float* hwWg   = (const float*)d_in[24];
  const float* hwbg   = (const float*)d_in[25];
  const float* emW    = (const float*)d_in[26];
  const float* emb    = (const float*)d_in[27];
  const float* trans  = (const float*)d_in[28];

  // workspace layout (floats)
  float* p = (float*)d_ws;
  size_t o = 0;
  float* CWf  = p + o; o += 100*1024;
  float* CWb  = p + o; o += 100*1024;
  uint2* WHcf = (uint2*)(p + o); o += 264*256*2;
  uint2* WHcb = (uint2*)(p + o); o += 264*256*2;
  uint2* WHwf = (uint2*)(p + o); o += 264*256*2;
  uint2* WHwb = (uint2*)(p + o); o += 264*256*2;
  float* Wpf  = p + o; o += 1024*DWPn;
  float* Wpb  = p + o; o += 1024*DWPn;
  int*   posf = (int*)(p + o); o += 64*512;
  int*   posb = (int*)(p + o); o += 64*512;
  float* sub  = p + o; o += (size_t)64*128*512;   // reused later as hout
  float* hwz  = p + o; o += (size_t)8192*1024;    // reused later as wXf
  float* wq   = p + o; o += (size_t)8192*DWPn;    // reused later as em/emWp/embp
  float* wXb  = p + o; o += (size_t)8192*1024;
  float* wXf  = hwz;            // alias: hwz dead after k_hwelt
  float* hout = sub;            // alias: sub dead after k_wasm
  float* em   = wq;             // alias: wq dead after word-Xih gemm
  float* emWp = wq + 8192*64;
  float* embp = emWp + 64*512;

  float* out  = (float*)d_out;

  hipMemsetAsync(sub, 0, (size_t)64*128*512*sizeof(float), stream);

  k_prep_cw <<<dim3(100,2), 256, 0, stream>>>(ceW, fcWih, fcb, bcWih, bcb, CWf, CWb);
  k_prep_wt <<<dim3(256,4), 256, 0, stream>>>(fcWhh, bcWhh, wfWhh, wbWhh, WHcf, WHcb, WHwf, WHwb);
  k_pad     <<<dim3(1024,2), 256, 0, stream>>>(wfWih, wbWih, Wpf, Wpb);
  k_prep_pos<<<dim3(64,2), 64, 0, stream>>>(cmakf, cmakb, posf, posb);

  k_char_lstm<<<64, 1024, 0, stream>>>(cmapsf, cmapsb, CWf, CWb, WHcf, WHcb, posf, posb, sub);

  // highway
  k_gemm<<<dim3(64,8,2), 256, 0, stream>>>(sub, 512, 512, 512,
                                           hwWt, hwWg, hwbt, hwbg,
                                           hwz, hwz+512, 1024);
  k_hwelt<<<4096, 256, 0, stream>>>(hwz, sub);

  k_wasm<<<8192, 256, 0, stream>>>(wmap, weW, sub, wq);

  // word input projections
  k_gemm<<<dim3(64,16,2), 256, 0, stream>>>(wq, DWPn, DWPn, DWPn,
                                            Wpf, Wpb, wfb, wbb,
                                            wXf, wXb, 1024);

  k_word_lstm<<<64, 1024, 0, stream>>>(wXf, wXb, WHwf, WHwb, hout);

  // em = hout @ emW^T + emb (padded to 64 tags), ld 64
  k_pad_em<<<64, 256, 0, stream>>>(emW, emb, emWp, embp);
  k_gemm<<<dim3(64,1,1), 256, 0, stream>>>(hout, 512, 512, 512,
                                           emWp, emWp, embp, embp,
                                           em, em, 64);

  k_crf<<<8192, 256, 0, stream>>>(em, trans, out);
  k_tail<<<65, 256, 0, stream>>>(tmaps, lengths, tmapc, out + (size_t)20480000);
}

// Round 5
// 3940.912 us; speedup vs baseline: 1.4792x; 1.4792x over previous
//
#include <hip/hip_runtime.h>
#include <math.h>

#define Bn 64
#define Tn 128
#define TCn 512
#define CEn 64
#define CHn 256
#define TAGSn 50
#define DWPn 640   // word-LSTM input dim padded 612 -> 640

typedef float f32x4 __attribute__((ext_vector_type(4)));

__device__ __forceinline__ float sigf(float x){ return 1.0f/(1.0f+expf(-x)); }

// float -> OCP e4m3fn (RNE, denormal-correct, saturating)
__device__ __forceinline__ unsigned f2e4m3(float x){
  unsigned s = (__float_as_uint(x) >> 24) & 0x80u;
  float ax = fabsf(x);
  if (ax < 0.015625f){                 // subnormal: steps of 2^-9
    int q = (int)rintf(ax * 512.f);
    if (q >= 8) return s | 0x08u;
    return s | (unsigned)q;
  }
  if (ax > 464.f) return s | 0x7eu;    // saturate to 448
  int e; float mfr = frexpf(ax, &e);   // ax = mfr*2^e, mfr in [0.5,1)
  int q = (int)rintf(mfr * 16.f);      // 8..16
  int E = e + 6;
  if (q == 16){ q = 8; E += 1; }
  if (E > 15 || (E == 15 && q == 15)) return s | 0x7eu;
  return s | (unsigned)((E<<3) | (q - 8));
}

// ---------------------------------------------------------------------------
// CW[d][c][u*4+k] = b_d[k*256+u] + sum_e ceW[c][e]*Wih_d[k*256+u][e]
__global__ void k_prep_cw(const float* __restrict__ ceW,
                          const float* __restrict__ Wf, const float* __restrict__ bf,
                          const float* __restrict__ Wb, const float* __restrict__ bb,
                          float* __restrict__ CWf, float* __restrict__ CWb){
  const int c = blockIdx.x, u = threadIdx.x;
  const float* Wih  = blockIdx.y ? Wb : Wf;
  const float* bias = blockIdx.y ? bb : bf;
  float*       CW   = blockIdx.y ? CWb : CWf;
  __shared__ float ce[CEn];
  if (u < CEn) ce[u] = ceW[c*CEn + u];
  __syncthreads();
  float a[4];
  #pragma unroll
  for (int k=0;k<4;k++){
    const float* wr = Wih + (size_t)(k*CHn+u)*CEn;
    float s = bias[k*CHn+u];
    #pragma unroll 4
    for (int e=0;e<CEn;e++) s += ce[e]*wr[e];
    a[k]=s;
  }
  ((float4*)CW)[c*CHn+u] = make_float4(a[0],a[1],a[2],a[3]);
}

// fp8 e4m3 Whh (elementwise, no transpose): out[n][k] byte = e4m3(Whh[n][k])
// grid (512,4) x 256: each thread converts 2 consecutive elements (131072 pairs)
__global__ void k_prep_w8(const float* __restrict__ W0, const float* __restrict__ W1,
                          const float* __restrict__ W2, const float* __restrict__ W3,
                          unsigned short* __restrict__ O0, unsigned short* __restrict__ O1,
                          unsigned short* __restrict__ O2, unsigned short* __restrict__ O3){
  const int w = blockIdx.y;
  const float* W = (w==0)?W0:(w==1)?W1:(w==2)?W2:W3;
  unsigned short* O = (w==0)?O0:(w==1)?O1:(w==2)?O2:O3;
  const int i = blockIdx.x*256 + threadIdx.x;      // 131072 pairs
  const float a = W[2*i], b = W[2*i+1];
  O[i] = (unsigned short)(f2e4m3(a) | (f2e4m3(b)<<8));
}

// pad word Wih (1024,612) -> (1024,640)
__global__ void k_pad(const float* __restrict__ Wf, const float* __restrict__ Wb,
                      float* __restrict__ Pf, float* __restrict__ Pb){
  const int j = blockIdx.x;
  const float* Win  = blockIdx.y ? Wb : Wf;
  float*       Wout = blockIdx.y ? Pb : Pf;
  for (int col=threadIdx.x; col<DWPn; col+=256)
    Wout[(size_t)j*DWPn+col] = (col<612) ? Win[(size_t)j*612+col] : 0.f;
}

// pad emW (50,512)->(64,512), emb (50)->(64)
__global__ void k_pad_em(const float* __restrict__ emW, const float* __restrict__ emb,
                         float* __restrict__ Wp, float* __restrict__ bp){
  const int j = blockIdx.x;
  for (int col=threadIdx.x; col<512; col+=256)
    Wp[(size_t)j*512+col] = (j<TAGSn) ? emW[(size_t)j*512+col] : 0.f;
  if (threadIdx.x==0) bp[j] = (j<TAGSn) ? emb[j] : 0.f;
}

// stable-compaction ranks from cmakers only; grid (64,2), 64 threads (1 wave)
__global__ void k_prep_pos(const float* __restrict__ cmf, const float* __restrict__ cmb,
                           int* __restrict__ pf, int* __restrict__ pb){
  const float* cm = blockIdx.y ? cmb : cmf;
  int* pos        = blockIdx.y ? pb : pf;
  const int n = blockIdx.x, lane = threadIdx.x;
  int base = 0;
  for (int c=0;c<TCn/64;c++){
    int t = c*64 + lane;
    bool m = cm[n*TCn+t] != 0.f;
    unsigned long long bal = __ballot(m);
    int before = __popcll(bal & ((1ULL<<lane)-1ULL));
    int r = base + before;
    pos[n*TCn+t] = (m && r < Tn) ? r : -1;
    base += __popcll(bal);
  }
}

// ---------------------------------------------------------------------------
// char LSTM via MFMA, fp8 register-resident weights.
// 8 blocks = dir(2) x rowgroup(4, M=16 seqs). 1024 threads = 16 waves.
// Wave wv owns gate-cols [wv*64, wv*64+64). Per step:
//   MFMA: z[16][1024] = h_fp8[16][256] @ W8^T   (acc f32)
//   gate: thread (u=t&255, rowg=t>>8) does rows rowg*4+r; c stays f32.
__global__ __launch_bounds__(1024, 4)
void k_char_lstm(const int* __restrict__ cmf, const int* __restrict__ cmb,
                 const float* __restrict__ CWf, const float* __restrict__ CWb,
                 const unsigned char* __restrict__ W8f, const unsigned char* __restrict__ W8b,
                 const int* __restrict__ posf, const int* __restrict__ posb,
                 float* __restrict__ sub){
  const int dir = blockIdx.x >> 2, mg = blockIdx.x & 3;
  const int n0 = mg*16;
  const int t1 = threadIdx.x;
  const int wv = t1 >> 6, lane = t1 & 63;
  const int m = lane & 15, g = lane >> 4;
  const int*    cm  = dir ? cmb : cmf;
  const float4* CW  = (const float4*)(dir ? CWb : CWf);
  const unsigned char* W8 = dir ? W8b : W8f;
  const int*    pos = dir ? posb : posf;
  const int dofs = dir ? CHn : 0;

  __shared__ float zbuf[16][1033];
  __shared__ unsigned long hbufl[2][16][32];   // fp8 h, chunk index XOR row

  // register-resident B fragments: B[k][n]=Whh[n][k], n=wv*64+nt*16+m, k=kt*32+g*8+i
  long Bfr[4][8];
  #pragma unroll
  for (int nt=0;nt<4;nt++)
    #pragma unroll
    for (int kt=0;kt<8;kt++)
      Bfr[nt][kt] = *(const long*)(W8 + (size_t)(wv*64 + nt*16 + m)*256 + kt*32 + g*8);

  if (t1 < 512) ((unsigned long*)hbufl)[t1] = 0ul;   // zero hbuf[0]
  const int u = t1 & 255, rowg = t1 >> 8;
  float cst[4] = {0.f,0.f,0.f,0.f};
  int par = 0;
  __syncthreads();

  for (int t=0;t<TCn;t++){
    // prefetch input projection + scatter pos (used in gate phase)
    int pp[4]; float4 cw[4];
    #pragma unroll
    for (int r=0;r<4;r++){
      const int seq = n0 + rowg*4 + r;
      const int ci = cm[seq*TCn + t];
      pp[r] = pos[seq*TCn + t];
      cw[r] = CW[(size_t)ci*CHn + u];
    }
    // MFMA phase
    f32x4 acc[4];
    #pragma unroll
    for (int nt=0;nt<4;nt++){ acc[nt][0]=0.f; acc[nt][1]=0.f; acc[nt][2]=0.f; acc[nt][3]=0.f; }
    #pragma unroll
    for (int kt=0;kt<8;kt++){
      const long afr = (long)hbufl[par][m][(kt*4+g)^m];
      #pragma unroll
      for (int nt=0;nt<4;nt++)
        acc[nt] = __builtin_amdgcn_mfma_f32_16x16x32_fp8_fp8(afr, Bfr[nt][kt], acc[nt], 0,0,0);
    }
    #pragma unroll
    for (int nt=0;nt<4;nt++){
      const int col = wv*64 + nt*16 + m;
      #pragma unroll
      for (int rg=0;rg<4;rg++)
        zbuf[g*4+rg][col] = acc[nt][rg];
    }
    __syncthreads();
    // gate phase
    #pragma unroll
    for (int r=0;r<4;r++){
      const int row = rowg*4 + r;
      const float zi = zbuf[row][u      ] + cw[r].x;
      const float zf = zbuf[row][256+u  ] + cw[r].y;
      const float zg = zbuf[row][512+u  ] + cw[r].z;
      const float zo = zbuf[row][768+u  ] + cw[r].w;
      cst[r] = sigf(zf)*cst[r] + sigf(zi)*tanhf(zg);
      const float hn = sigf(zo)*tanhf(cst[r]);
      ((unsigned char*)&hbufl[par^1][row][0])[(((u>>3)^row)<<3)|(u&7)] = (unsigned char)f2e4m3(hn);
      if (pp[r]>=0) sub[(size_t)((n0+row)*Tn+pp[r])*512 + dofs + u] = hn;
    }
    __syncthreads();
    par ^= 1;
  }
}

// ---------------------------------------------------------------------------
// word LSTM via MFMA: scans B=64 steps, batch T=128 rows.
// 16 blocks = dir(2) x rowgroup(8, M=16 word-positions). 1024 threads.
__global__ __launch_bounds__(1024, 4)
void k_word_lstm(const float* __restrict__ wXf, const float* __restrict__ wXb,
                 const unsigned char* __restrict__ W8f, const unsigned char* __restrict__ W8b,
                 float* __restrict__ hout){
  const int dir = blockIdx.x >> 3, mg = blockIdx.x & 7;
  const int t0r = mg*16;
  const int t1 = threadIdx.x;
  const int wv = t1 >> 6, lane = t1 & 63;
  const int m = lane & 15, g = lane >> 4;
  const float* wX = dir ? wXb : wXf;
  const unsigned char* W8 = dir ? W8b : W8f;
  const int dofs = dir ? CHn : 0;

  __shared__ float zbuf[16][1033];
  __shared__ unsigned long hbufl[2][16][32];

  long Bfr[4][8];
  #pragma unroll
  for (int nt=0;nt<4;nt++)
    #pragma unroll
    for (int kt=0;kt<8;kt++)
      Bfr[nt][kt] = *(const long*)(W8 + (size_t)(wv*64 + nt*16 + m)*256 + kt*32 + g*8);

  if (t1 < 512) ((unsigned long*)hbufl)[t1] = 0ul;
  const int u = t1 & 255, rowg = t1 >> 8;
  float cst[4] = {0.f,0.f,0.f,0.f};
  int par = 0;
  __syncthreads();

  for (int s=0;s<64;s++){
    const int n = dir ? (63-s) : s;
    float4 zin[4];
    #pragma unroll
    for (int r=0;r<4;r++){
      const float* xp = wX + (size_t)(n*Tn + t0r + rowg*4 + r)*1024 + u;
      zin[r] = make_float4(xp[0], xp[256], xp[512], xp[768]);
    }
    f32x4 acc[4];
    #pragma unroll
    for (int nt=0;nt<4;nt++){ acc[nt][0]=0.f; acc[nt][1]=0.f; acc[nt][2]=0.f; acc[nt][3]=0.f; }
    #pragma unroll
    for (int kt=0;kt<8;kt++){
      const long afr = (long)hbufl[par][m][(kt*4+g)^m];
      #pragma unroll
      for (int nt=0;nt<4;nt++)
        acc[nt] = __builtin_amdgcn_mfma_f32_16x16x32_fp8_fp8(afr, Bfr[nt][kt], acc[nt], 0,0,0);
    }
    #pragma unroll
    for (int nt=0;nt<4;nt++){
      const int col = wv*64 + nt*16 + m;
      #pragma unroll
      for (int rg=0;rg<4;rg++)
        zbuf[g*4+rg][col] = acc[nt][rg];
    }
    __syncthreads();
    #pragma unroll
    for (int r=0;r<4;r++){
      const int row = rowg*4 + r;
      const float zi = zbuf[row][u      ] + zin[r].x;
      const float zf = zbuf[row][256+u  ] + zin[r].y;
      const float zg = zbuf[row][512+u  ] + zin[r].z;
      const float zo = zbuf[row][768+u  ] + zin[r].w;
      cst[r] = sigf(zf)*cst[r] + sigf(zi)*tanhf(zg);
      const float hn = sigf(zo)*tanhf(cst[r]);
      ((unsigned char*)&hbufl[par^1][row][0])[(((u>>3)^row)<<3)|(u&7)] = (unsigned char)f2e4m3(hn);
      hout[(size_t)(n*Tn + t0r + row)*512 + dofs + u] = hn;
    }
    __syncthreads();
    par ^= 1;
  }
}

// ---------------------------------------------------------------------------
// generic fp32 GEMM: C[m][n] = bias[n] + sum_k A[m][k]*W[n][k]
__global__ __launch_bounds__(256)
void k_gemm(const float* __restrict__ A, int lda, int K, int ldw,
            const float* __restrict__ W0, const float* __restrict__ W1,
            const float* __restrict__ b0, const float* __restrict__ b1,
            float* __restrict__ C0, float* __restrict__ C1, int ldc){
  const float* W    = blockIdx.z ? W1 : W0;
  const float* bias = blockIdx.z ? b1 : b0;
  float*       C    = blockIdx.z ? C1 : C0;
  const int m0 = blockIdx.x*128, n0 = blockIdx.y*64;
  __shared__ float As[32][132];
  __shared__ float Bs[32][68];
  const int tid = threadIdx.x;
  float acc[8][4];
  #pragma unroll
  for (int i=0;i<8;i++){
    #pragma unroll
    for (int j=0;j<4;j++) acc[i][j]=0.f;
  }
  const int tm = tid & 15, tn = tid >> 4;
  for (int kc=0; kc<K; kc+=32){
    #pragma unroll
    for (int it=0; it<4; it++){
      int fl = tid + it*256; int r = fl>>3; int kq = fl&7;
      float4 v = *(const float4*)(A + (size_t)(m0+r)*lda + kc + kq*4);
      As[kq*4+0][r]=v.x; As[kq*4+1][r]=v.y; As[kq*4+2][r]=v.z; As[kq*4+3][r]=v.w;
    }
    #pragma unroll
    for (int it=0; it<2; it++){
      int fl = tid + it*256; int r = fl>>3; int kq = fl&7;
      float4 v = *(const float4*)(W + (size_t)(n0+r)*ldw + kc + kq*4);
      Bs[kq*4+0][r]=v.x; Bs[kq*4+1][r]=v.y; Bs[kq*4+2][r]=v.z; Bs[kq*4+3][r]=v.w;
    }
    __syncthreads();
    #pragma unroll
    for (int k=0;k<32;k++){
      float a[8], b[4];
      *(float4*)(a)   = *(const float4*)(&As[k][tm*8]);
      *(float4*)(a+4) = *(const float4*)(&As[k][tm*8+4]);
      *(float4*)(b)   = *(const float4*)(&Bs[k][tn*4]);
      #pragma unroll
      for (int i=0;i<8;i++){
        #pragma unroll
        for (int j=0;j<4;j++) acc[i][j] += a[i]*b[j];
      }
    }
    __syncthreads();
  }
  float4 bv = *(const float4*)(bias + n0 + tn*4);
  #pragma unroll
  for (int i=0;i<8;i++){
    float4 o = make_float4(acc[i][0]+bv.x, acc[i][1]+bv.y, acc[i][2]+bv.z, acc[i][3]+bv.w);
    *(float4*)(C + (size_t)(m0+tm*8+i)*ldc + n0 + tn*4) = o;
  }
}

// highway elementwise: sub = g*relu(zt) + (1-g)*sub
__global__ __launch_bounds__(256)
void k_hwelt(const float* __restrict__ hwz, float* __restrict__ sub){
  const int idx = blockIdx.x*256 + threadIdx.x;
  const int m = idx >> 7, j4 = idx & 127;
  float4 s  = ((const float4*)sub)[idx];
  float4 zt = ((const float4*)hwz)[(size_t)m*256 + j4];
  float4 zg = ((const float4*)hwz)[(size_t)m*256 + 128 + j4];
  float4 o;
  { float g=sigf(zg.x), tr=fmaxf(zt.x,0.f); o.x = g*tr + (1.f-g)*s.x; }
  { float g=sigf(zg.y), tr=fmaxf(zt.y,0.f); o.y = g*tr + (1.f-g)*s.y; }
  { float g=sigf(zg.z), tr=fmaxf(zt.z,0.f); o.z = g*tr + (1.f-g)*s.z; }
  { float g=sigf(zg.w), tr=fmaxf(zt.w,0.f); o.w = g*tr + (1.f-g)*s.w; }
  ((float4*)sub)[idx] = o;
}

// assemble padded word input
__global__ void k_wasm(const int* __restrict__ wmap, const float* __restrict__ weW,
                       const float* __restrict__ sub, float* __restrict__ w){
  const int m = blockIdx.x;
  const int wi = wmap[m];
  for (int col=threadIdx.x; col<DWPn; col+=256){
    float v = 0.f;
    if (col < 100)      v = weW[(size_t)wi*100 + col];
    else if (col < 612) v = sub[(size_t)m*512 + (col-100)];
    w[(size_t)m*DWPn + col] = v;
  }
}

// crf[m][a][b] = em[m][b] + trans[a][b] ; em ld=64
__global__ __launch_bounds__(256)
void k_crf(const float* __restrict__ em, const float* __restrict__ trans,
           float* __restrict__ out){
  const int m = blockIdx.x;
  __shared__ float er[TAGSn];
  if (threadIdx.x < TAGSn) er[threadIdx.x] = em[(size_t)m*64 + threadIdx.x];
  __syncthreads();
  float* o = out + (size_t)m*2500;
  for (int r=threadIdx.x; r<2500; r+=256)
    o[r] = er[r % TAGSn] + trans[r];
}

// int tail outputs as floats
__global__ void k_tail(const int* __restrict__ tm, const int* __restrict__ ln,
                       const int* __restrict__ tc, float* __restrict__ out){
  const int i = blockIdx.x*256 + threadIdx.x;
  if (i < 8192)       out[i] = (float)tm[i];
  else if (i < 8256)  out[i] = (float)ln[i-8192];
  else if (i < 16448) out[i] = (float)tc[i-8256];
}

// ---------------------------------------------------------------------------
extern "C" void kernel_launch(void* const* d_in, const int* in_sizes, int n_in,
                              void* d_out, int out_size, void* d_ws, size_t ws_size,
                              hipStream_t stream){
  (void)in_sizes; (void)n_in; (void)out_size; (void)ws_size;
  const int*   wmap   = (const int*)d_in[0];
  const int*   cmapsf = (const int*)d_in[1];
  const int*   cmapsb = (const int*)d_in[2];
  const float* cmakf  = (const float*)d_in[3];
  const float* cmakb  = (const float*)d_in[4];
  const int*   tmaps  = (const int*)d_in[5];
  const int*   tmapc  = (const int*)d_in[6];
  const int*   lengths= (const int*)d_in[7];
  const float* ceW    = (const float*)d_in[8];
  const float* fcWih  = (const float*)d_in[9];
  const float* fcWhh  = (const float*)d_in[10];
  const float* fcb    = (const float*)d_in[11];
  const float* bcWih  = (const float*)d_in[12];
  const float* bcWhh  = (const float*)d_in[13];
  const float* bcb    = (const float*)d_in[14];
  const float* weW    = (const float*)d_in[15];
  const float* wfWih  = (const float*)d_in[16];
  const float* wfWhh  = (const float*)d_in[17];
  const float* wfb    = (const float*)d_in[18];
  const float* wbWih  = (const float*)d_in[19];
  const float* wbWhh  = (const float*)d_in[20];
  const float* wbb    = (const float*)d_in[21];
  const float* hwWt   = (const float*)d_in[22];
  const float* hwbt   = (const float*)d_in[23];
  const float* hwWg   = (const float*)d_in[24];
  const float* hwbg   = (const float*)d_in[25];
  const float* emW    = (const float*)d_in[26];
  const float* emb    = (const float*)d_in[27];
  const float* trans  = (const float*)d_in[28];

  // workspace layout (floats)
  float* p = (float*)d_ws;
  size_t o = 0;
  float* CWf  = p + o; o += 100*1024;
  float* CWb  = p + o; o += 100*1024;
  unsigned short* W8cf = (unsigned short*)(p + o); o += 65536;   // 1024*256 bytes
  unsigned short* W8cb = (unsigned short*)(p + o); o += 65536;
  unsigned short* W8wf = (unsigned short*)(p + o); o += 65536;
  unsigned short* W8wb = (unsigned short*)(p + o); o += 65536;
  float* Wpf  = p + o; o += 1024*DWPn;
  float* Wpb  = p + o; o += 1024*DWPn;
  int*   posf = (int*)(p + o); o += 64*512;
  int*   posb = (int*)(p + o); o += 64*512;
  float* sub  = p + o; o += (size_t)64*128*512;   // reused later as hout
  float* hwz  = p + o; o += (size_t)8192*1024;    // reused later as wXf
  float* wq   = p + o; o += (size_t)8192*DWPn;    // reused later as em/emWp/embp
  float* wXb  = p + o; o += (size_t)8192*1024;
  float* wXf  = hwz;            // alias: hwz dead after k_hwelt
  float* hout = sub;            // alias: sub dead after k_wasm
  float* em   = wq;             // alias: wq dead after word-Xih gemm
  float* emWp = wq + 8192*64;
  float* embp = emWp + 64*512;

  float* out  = (float*)d_out;

  hipMemsetAsync(sub, 0, (size_t)64*128*512*sizeof(float), stream);

  k_prep_cw <<<dim3(100,2), 256, 0, stream>>>(ceW, fcWih, fcb, bcWih, bcb, CWf, CWb);
  k_prep_w8 <<<dim3(512,4), 256, 0, stream>>>(fcWhh, bcWhh, wfWhh, wbWhh,
                                              W8cf, W8cb, W8wf, W8wb);
  k_pad     <<<dim3(1024,2), 256, 0, stream>>>(wfWih, wbWih, Wpf, Wpb);
  k_prep_pos<<<dim3(64,2), 64, 0, stream>>>(cmakf, cmakb, posf, posb);

  k_char_lstm<<<8, 1024, 0, stream>>>(cmapsf, cmapsb, CWf, CWb,
                                      (const unsigned char*)W8cf, (const unsigned char*)W8cb,
                                      posf, posb, sub);

  // highway
  k_gemm<<<dim3(64,8,2), 256, 0, stream>>>(sub, 512, 512, 512,
                                           hwWt, hwWg, hwbt, hwbg,
                                           hwz, hwz+512, 1024);
  k_hwelt<<<4096, 256, 0, stream>>>(hwz, sub);

  k_wasm<<<8192, 256, 0, stream>>>(wmap, weW, sub, wq);

  // word input projections
  k_gemm<<<dim3(64,16,2), 256, 0, stream>>>(wq, DWPn, DWPn, DWPn,
                                            Wpf, Wpb, wfb, wbb,
                                            wXf, wXb, 1024);

  k_word_lstm<<<16, 1024, 0, stream>>>(wXf, wXb,
                                       (const unsigned char*)W8wf, (const unsigned char*)W8wb,
                                       hout);

  // em = hout @ emW^T + emb (padded to 64 tags), ld 64
  k_pad_em<<<64, 256, 0, stream>>>(emW, emb, emWp, embp);
  k_gemm<<<dim3(64,1,1), 256, 0, stream>>>(hout, 512, 512, 512,
                                           emWp, emWp, embp, embp,
                                           em, em, 64);

  k_crf<<<8192, 256, 0, stream>>>(em, trans, out);
  k_tail<<<65, 256, 0, stream>>>(tmaps, lengths, tmapc, out + (size_t)20480000);
}

// Round 6
// 1569.307 us; speedup vs baseline: 3.7147x; 2.5112x over previous
//
#include <hip/hip_runtime.h>
#include <math.h>

#define Bn 64
#define Tn 128
#define TCn 512
#define CEn 64
#define CHn 256
#define TAGSn 50
#define DWPn 640   // word-LSTM input dim padded 612 -> 640

typedef float f32x4 __attribute__((ext_vector_type(4)));

__device__ __forceinline__ float sigf(float x){ return 1.0f/(1.0f+expf(-x)); }

// fast gate nonlinearities: v_exp_f32 + v_rcp_f32, endpoint-safe
__device__ __forceinline__ float fsig(float x){
  return __builtin_amdgcn_rcpf(1.f + exp2f(-1.4426950408889634f*x));
}
__device__ __forceinline__ float ftanh(float x){
  return 1.f - 2.f*__builtin_amdgcn_rcpf(1.f + exp2f(2.885390081777927f*x));
}

// float -> OCP e4m3fn (RNE, denormal-correct, saturating)
__device__ __forceinline__ unsigned f2e4m3(float x){
  unsigned s = (__float_as_uint(x) >> 24) & 0x80u;
  float ax = fabsf(x);
  if (ax < 0.015625f){                 // subnormal: steps of 2^-9
    int q = (int)rintf(ax * 512.f);
    if (q >= 8) return s | 0x08u;
    return s | (unsigned)q;
  }
  if (ax > 464.f) return s | 0x7eu;    // saturate to 448
  int e; float mfr = frexpf(ax, &e);   // ax = mfr*2^e, mfr in [0.5,1)
  int q = (int)rintf(mfr * 16.f);      // 8..16
  int E = e + 6;
  if (q == 16){ q = 8; E += 1; }
  if (E > 15 || (E == 15 && q == 15)) return s | 0x7eu;
  return s | (unsigned)((E<<3) | (q - 8));
}

// ---------------------------------------------------------------------------
// CW[d][c][u*4+k] = b_d[k*256+u] + sum_e ceW[c][e]*Wih_d[k*256+u][e]
__global__ void k_prep_cw(const float* __restrict__ ceW,
                          const float* __restrict__ Wf, const float* __restrict__ bf,
                          const float* __restrict__ Wb, const float* __restrict__ bb,
                          float* __restrict__ CWf, float* __restrict__ CWb){
  const int c = blockIdx.x, u = threadIdx.x;
  const float* Wih  = blockIdx.y ? Wb : Wf;
  const float* bias = blockIdx.y ? bb : bf;
  float*       CW   = blockIdx.y ? CWb : CWf;
  __shared__ float ce[CEn];
  if (u < CEn) ce[u] = ceW[c*CEn + u];
  __syncthreads();
  float a[4];
  #pragma unroll
  for (int k=0;k<4;k++){
    const float* wr = Wih + (size_t)(k*CHn+u)*CEn;
    float s = bias[k*CHn+u];
    #pragma unroll 4
    for (int e=0;e<CEn;e++) s += ce[e]*wr[e];
    a[k]=s;
  }
  ((float4*)CW)[c*CHn+u] = make_float4(a[0],a[1],a[2],a[3]);
}

// fp8 e4m3 Whh (elementwise, no transpose): out[n][k] byte = e4m3(Whh[n][k])
// grid (512,4) x 256: each thread converts 2 consecutive elements (131072 pairs)
__global__ void k_prep_w8(const float* __restrict__ W0, const float* __restrict__ W1,
                          const float* __restrict__ W2, const float* __restrict__ W3,
                          unsigned short* __restrict__ O0, unsigned short* __restrict__ O1,
                          unsigned short* __restrict__ O2, unsigned short* __restrict__ O3){
  const int w = blockIdx.y;
  const float* W = (w==0)?W0:(w==1)?W1:(w==2)?W2:W3;
  unsigned short* O = (w==0)?O0:(w==1)?O1:(w==2)?O2:O3;
  const int i = blockIdx.x*256 + threadIdx.x;      // 131072 pairs
  const float a = W[2*i], b = W[2*i+1];
  O[i] = (unsigned short)(f2e4m3(a) | (f2e4m3(b)<<8));
}

// pad word Wih (1024,612) -> (1024,640)
__global__ void k_pad(const float* __restrict__ Wf, const float* __restrict__ Wb,
                      float* __restrict__ Pf, float* __restrict__ Pb){
  const int j = blockIdx.x;
  const float* Win  = blockIdx.y ? Wb : Wf;
  float*       Wout = blockIdx.y ? Pb : Pf;
  for (int col=threadIdx.x; col<DWPn; col+=256)
    Wout[(size_t)j*DWPn+col] = (col<612) ? Win[(size_t)j*612+col] : 0.f;
}

// pad emW (50,512)->(64,512), emb (50)->(64)
__global__ void k_pad_em(const float* __restrict__ emW, const float* __restrict__ emb,
                         float* __restrict__ Wp, float* __restrict__ bp){
  const int j = blockIdx.x;
  for (int col=threadIdx.x; col<512; col+=256)
    Wp[(size_t)j*512+col] = (j<TAGSn) ? emW[(size_t)j*512+col] : 0.f;
  if (threadIdx.x==0) bp[j] = (j<TAGSn) ? emb[j] : 0.f;
}

// stable-compaction ranks from cmakers only; grid (64,2), 64 threads (1 wave)
__global__ void k_prep_pos(const float* __restrict__ cmf, const float* __restrict__ cmb,
                           int* __restrict__ pf, int* __restrict__ pb){
  const float* cm = blockIdx.y ? cmb : cmf;
  int* pos        = blockIdx.y ? pb : pf;
  const int n = blockIdx.x, lane = threadIdx.x;
  int base = 0;
  for (int c=0;c<TCn/64;c++){
    int t = c*64 + lane;
    bool m = cm[n*TCn+t] != 0.f;
    unsigned long long bal = __ballot(m);
    int before = __popcll(bal & ((1ULL<<lane)-1ULL));
    int r = base + before;
    pos[n*TCn+t] = (m && r < Tn) ? r : -1;
    base += __popcll(bal);
  }
}

// ---------------------------------------------------------------------------
// char LSTM via MFMA, fp8 register-resident weights, M=4 rows/block.
// 32 blocks = dir(2) x rowgroup(16, 4 seqs each). 1024 threads = 16 waves.
// Wave wv owns gate-cols [wv*64, wv*64+64). A-rows 4..15 of hbuf stay zero.
// Gate phase: thread (u=t&255, rw=t>>8) handles exactly one (row rw, unit u).
__global__ __launch_bounds__(1024, 4)
void k_char_lstm(const int* __restrict__ cmf, const int* __restrict__ cmb,
                 const float* __restrict__ CWf, const float* __restrict__ CWb,
                 const unsigned char* __restrict__ W8f, const unsigned char* __restrict__ W8b,
                 const int* __restrict__ posf, const int* __restrict__ posb,
                 float* __restrict__ sub){
  const int dir = blockIdx.x >> 4, mg = blockIdx.x & 15;
  const int n0 = mg*4;
  const int t1 = threadIdx.x;
  const int wv = t1 >> 6, lane = t1 & 63;
  const int m = lane & 15, g = lane >> 4;
  const int*    cm  = dir ? cmb : cmf;
  const float4* CW  = (const float4*)(dir ? CWb : CWf);
  const unsigned char* W8 = dir ? W8b : W8f;
  const int*    pos = dir ? posb : posf;
  const int dofs = dir ? CHn : 0;

  __shared__ float zbuf[4][1040];
  __shared__ unsigned long hbufl[2][16][32];   // fp8 h, chunk index XOR row

  // register-resident B fragments: B[k][n]=Whh[n][k], n=wv*64+nt*16+m, k=kt*32+g*8+i
  long Bfr[4][8];
  #pragma unroll
  for (int nt=0;nt<4;nt++)
    #pragma unroll
    for (int kt=0;kt<8;kt++)
      Bfr[nt][kt] = *(const long*)(W8 + (size_t)(wv*64 + nt*16 + m)*256 + kt*32 + g*8);

  ((unsigned long*)hbufl)[t1] = 0ul;   // zero both buffers (1024 longs)
  const int u = t1 & 255, rw = t1 >> 8;
  float cst = 0.f;
  int par = 0;
  __syncthreads();

  for (int t=0;t<TCn;t++){
    // prefetch input projection + scatter pos (used in gate phase)
    const int seq = n0 + rw;
    const int ci = cm[seq*TCn + t];
    const int pp = pos[seq*TCn + t];
    const float4 cw = CW[(size_t)ci*CHn + u];
    // MFMA phase
    f32x4 acc[4];
    #pragma unroll
    for (int nt=0;nt<4;nt++){ acc[nt][0]=0.f; acc[nt][1]=0.f; acc[nt][2]=0.f; acc[nt][3]=0.f; }
    #pragma unroll
    for (int kt=0;kt<8;kt++){
      const long afr = (long)hbufl[par][m][(kt*4+g)^m];
      #pragma unroll
      for (int nt=0;nt<4;nt++)
        acc[nt] = __builtin_amdgcn_mfma_f32_16x16x32_fp8_fp8(afr, Bfr[nt][kt], acc[nt], 0,0,0);
    }
    if (g==0){   // rows 0..3 live in lanes 0..15 (reg rg = row)
      #pragma unroll
      for (int nt=0;nt<4;nt++){
        const int col = wv*64 + nt*16 + m;
        #pragma unroll
        for (int rg=0;rg<4;rg++)
          zbuf[rg][col] = acc[nt][rg];
      }
    }
    __syncthreads();
    // gate phase: one (row,unit) per thread
    {
      const float zi = zbuf[rw][u      ] + cw.x;
      const float zf = zbuf[rw][256+u  ] + cw.y;
      const float zg = zbuf[rw][512+u  ] + cw.z;
      const float zo = zbuf[rw][768+u  ] + cw.w;
      cst = fsig(zf)*cst + fsig(zi)*ftanh(zg);
      const float hn = fsig(zo)*ftanh(cst);
      ((unsigned char*)&hbufl[par^1][rw][0])[(((u>>3)^rw)<<3)|(u&7)] = (unsigned char)f2e4m3(hn);
      if (pp>=0) sub[(size_t)(seq*Tn+pp)*512 + dofs + u] = hn;
    }
    __syncthreads();
    par ^= 1;
  }
}

// ---------------------------------------------------------------------------
// word LSTM via MFMA: scans B=64 steps, batch T=128 rows, M=4 rows/block.
// 64 blocks = dir(2) x rowgroup(32, 4 word-positions each). 1024 threads.
__global__ __launch_bounds__(1024, 4)
void k_word_lstm(const float* __restrict__ wXf, const float* __restrict__ wXb,
                 const unsigned char* __restrict__ W8f, const unsigned char* __restrict__ W8b,
                 float* __restrict__ hout){
  const int dir = blockIdx.x >> 5, mg = blockIdx.x & 31;
  const int t0r = mg*4;
  const int t1 = threadIdx.x;
  const int wv = t1 >> 6, lane = t1 & 63;
  const int m = lane & 15, g = lane >> 4;
  const float* wX = dir ? wXb : wXf;
  const unsigned char* W8 = dir ? W8b : W8f;
  const int dofs = dir ? CHn : 0;

  __shared__ float zbuf[4][1040];
  __shared__ unsigned long hbufl[2][16][32];

  long Bfr[4][8];
  #pragma unroll
  for (int nt=0;nt<4;nt++)
    #pragma unroll
    for (int kt=0;kt<8;kt++)
      Bfr[nt][kt] = *(const long*)(W8 + (size_t)(wv*64 + nt*16 + m)*256 + kt*32 + g*8);

  ((unsigned long*)hbufl)[t1] = 0ul;
  const int u = t1 & 255, rw = t1 >> 8;
  float cst = 0.f;
  int par = 0;
  __syncthreads();

  for (int s=0;s<64;s++){
    const int n = dir ? (63-s) : s;
    const float* xp = wX + (size_t)(n*Tn + t0r + rw)*1024 + u;
    const float4 zin = make_float4(xp[0], xp[256], xp[512], xp[768]);
    f32x4 acc[4];
    #pragma unroll
    for (int nt=0;nt<4;nt++){ acc[nt][0]=0.f; acc[nt][1]=0.f; acc[nt][2]=0.f; acc[nt][3]=0.f; }
    #pragma unroll
    for (int kt=0;kt<8;kt++){
      const long afr = (long)hbufl[par][m][(kt*4+g)^m];
      #pragma unroll
      for (int nt=0;nt<4;nt++)
        acc[nt] = __builtin_amdgcn_mfma_f32_16x16x32_fp8_fp8(afr, Bfr[nt][kt], acc[nt], 0,0,0);
    }
    if (g==0){
      #pragma unroll
      for (int nt=0;nt<4;nt++){
        const int col = wv*64 + nt*16 + m;
        #pragma unroll
        for (int rg=0;rg<4;rg++)
          zbuf[rg][col] = acc[nt][rg];
      }
    }
    __syncthreads();
    {
      const float zi = zbuf[rw][u      ] + zin.x;
      const float zf = zbuf[rw][256+u  ] + zin.y;
      const float zg = zbuf[rw][512+u  ] + zin.z;
      const float zo = zbuf[rw][768+u  ] + zin.w;
      cst = fsig(zf)*cst + fsig(zi)*ftanh(zg);
      const float hn = fsig(zo)*ftanh(cst);
      ((unsigned char*)&hbufl[par^1][rw][0])[(((u>>3)^rw)<<3)|(u&7)] = (unsigned char)f2e4m3(hn);
      hout[(size_t)(n*Tn + t0r + rw)*512 + dofs + u] = hn;
    }
    __syncthreads();
    par ^= 1;
  }
}

// ---------------------------------------------------------------------------
// generic fp32 GEMM: C[m][n] = bias[n] + sum_k A[m][k]*W[n][k]
__global__ __launch_bounds__(256)
void k_gemm(const float* __restrict__ A, int lda, int K, int ldw,
            const float* __restrict__ W0, const float* __restrict__ W1,
            const float* __restrict__ b0, const float* __restrict__ b1,
            float* __restrict__ C0, float* __restrict__ C1, int ldc){
  const float* W    = blockIdx.z ? W1 : W0;
  const float* bias = blockIdx.z ? b1 : b0;
  float*       C    = blockIdx.z ? C1 : C0;
  const int m0 = blockIdx.x*128, n0 = blockIdx.y*64;
  __shared__ float As[32][132];
  __shared__ float Bs[32][68];
  const int tid = threadIdx.x;
  float acc[8][4];
  #pragma unroll
  for (int i=0;i<8;i++){
    #pragma unroll
    for (int j=0;j<4;j++) acc[i][j]=0.f;
  }
  const int tm = tid & 15, tn = tid >> 4;
  for (int kc=0; kc<K; kc+=32){
    #pragma unroll
    for (int it=0; it<4; it++){
      int fl = tid + it*256; int r = fl>>3; int kq = fl&7;
      float4 v = *(const float4*)(A + (size_t)(m0+r)*lda + kc + kq*4);
      As[kq*4+0][r]=v.x; As[kq*4+1][r]=v.y; As[kq*4+2][r]=v.z; As[kq*4+3][r]=v.w;
    }
    #pragma unroll
    for (int it=0; it<2; it++){
      int fl = tid + it*256; int r = fl>>3; int kq = fl&7;
      float4 v = *(const float4*)(W + (size_t)(n0+r)*ldw + kc + kq*4);
      Bs[kq*4+0][r]=v.x; Bs[kq*4+1][r]=v.y; Bs[kq*4+2][r]=v.z; Bs[kq*4+3][r]=v.w;
    }
    __syncthreads();
    #pragma unroll
    for (int k=0;k<32;k++){
      float a[8], b[4];
      *(float4*)(a)   = *(const float4*)(&As[k][tm*8]);
      *(float4*)(a+4) = *(const float4*)(&As[k][tm*8+4]);
      *(float4*)(b)   = *(const float4*)(&Bs[k][tn*4]);
      #pragma unroll
      for (int i=0;i<8;i++){
        #pragma unroll
        for (int j=0;j<4;j++) acc[i][j] += a[i]*b[j];
      }
    }
    __syncthreads();
  }
  float4 bv = *(const float4*)(bias + n0 + tn*4);
  #pragma unroll
  for (int i=0;i<8;i++){
    float4 o = make_float4(acc[i][0]+bv.x, acc[i][1]+bv.y, acc[i][2]+bv.z, acc[i][3]+bv.w);
    *(float4*)(C + (size_t)(m0+tm*8+i)*ldc + n0 + tn*4) = o;
  }
}

// highway elementwise: sub = g*relu(zt) + (1-g)*sub
__global__ __launch_bounds__(256)
void k_hwelt(const float* __restrict__ hwz, float* __restrict__ sub){
  const int idx = blockIdx.x*256 + threadIdx.x;
  const int m = idx >> 7, j4 = idx & 127;
  float4 s  = ((const float4*)sub)[idx];
  float4 zt = ((const float4*)hwz)[(size_t)m*256 + j4];
  float4 zg = ((const float4*)hwz)[(size_t)m*256 + 128 + j4];
  float4 o;
  { float g=sigf(zg.x), tr=fmaxf(zt.x,0.f); o.x = g*tr + (1.f-g)*s.x; }
  { float g=sigf(zg.y), tr=fmaxf(zt.y,0.f); o.y = g*tr + (1.f-g)*s.y; }
  { float g=sigf(zg.z), tr=fmaxf(zt.z,0.f); o.z = g*tr + (1.f-g)*s.z; }
  { float g=sigf(zg.w), tr=fmaxf(zt.w,0.f); o.w = g*tr + (1.f-g)*s.w; }
  ((float4*)sub)[idx] = o;
}

// assemble padded word input
__global__ void k_wasm(const int* __restrict__ wmap, const float* __restrict__ weW,
                       const float* __restrict__ sub, float* __restrict__ w){
  const int m = blockIdx.x;
  const int wi = wmap[m];
  for (int col=threadIdx.x; col<DWPn; col+=256){
    float v = 0.f;
    if (col < 100)      v = weW[(size_t)wi*100 + col];
    else if (col < 612) v = sub[(size_t)m*512 + (col-100)];
    w[(size_t)m*DWPn + col] = v;
  }
}

// crf[m][a][b] = em[m][b] + trans[a][b] ; em ld=64
__global__ __launch_bounds__(256)
void k_crf(const float* __restrict__ em, const float* __restrict__ trans,
           float* __restrict__ out){
  const int m = blockIdx.x;
  __shared__ float er[TAGSn];
  if (threadIdx.x < TAGSn) er[threadIdx.x] = em[(size_t)m*64 + threadIdx.x];
  __syncthreads();
  float* o = out + (size_t)m*2500;
  for (int r=threadIdx.x; r<2500; r+=256)
    o[r] = er[r % TAGSn] + trans[r];
}

// int tail outputs as floats
__global__ void k_tail(const int* __restrict__ tm, const int* __restrict__ ln,
                       const int* __restrict__ tc, float* __restrict__ out){
  const int i = blockIdx.x*256 + threadIdx.x;
  if (i < 8192)       out[i] = (float)tm[i];
  else if (i < 8256)  out[i] = (float)ln[i-8192];
  else if (i < 16448) out[i] = (float)tc[i-8256];
}

// ---------------------------------------------------------------------------
extern "C" void kernel_launch(void* const* d_in, const int* in_sizes, int n_in,
                              void* d_out, int out_size, void* d_ws, size_t ws_size,
                              hipStream_t stream){
  (void)in_sizes; (void)n_in; (void)out_size; (void)ws_size;
  const int*   wmap   = (const int*)d_in[0];
  const int*   cmapsf = (const int*)d_in[1];
  const int*   cmapsb = (const int*)d_in[2];
  const float* cmakf  = (const float*)d_in[3];
  const float* cmakb  = (const float*)d_in[4];
  const int*   tmaps  = (const int*)d_in[5];
  const int*   tmapc  = (const int*)d_in[6];
  const int*   lengths= (const int*)d_in[7];
  const float* ceW    = (const float*)d_in[8];
  const float* fcWih  = (const float*)d_in[9];
  const float* fcWhh  = (const float*)d_in[10];
  const float* fcb    = (const float*)d_in[11];
  const float* bcWih  = (const float*)d_in[12];
  const float* bcWhh  = (const float*)d_in[13];
  const float* bcb    = (const float*)d_in[14];
  const float* weW    = (const float*)d_in[15];
  const float* wfWih  = (const float*)d_in[16];
  const float* wfWhh  = (const float*)d_in[17];
  const float* wfb    = (const float*)d_in[18];
  const float* wbWih  = (const float*)d_in[19];
  const float* wbWhh  = (const float*)d_in[20];
  const float* wbb    = (const float*)d_in[21];
  const float* hwWt   = (const float*)d_in[22];
  const float* hwbt   = (const float*)d_in[23];
  const float* hwWg   = (const float*)d_in[24];
  const float* hwbg   = (const float*)d_in[25];
  const float* emW    = (const float*)d_in[26];
  const float* emb    = (const float*)d_in[27];
  const float* trans  = (const float*)d_in[28];

  // workspace layout (floats)
  float* p = (float*)d_ws;
  size_t o = 0;
  float* CWf  = p + o; o += 100*1024;
  float* CWb  = p + o; o += 100*1024;
  unsigned short* W8cf = (unsigned short*)(p + o); o += 65536;   // 1024*256 bytes
  unsigned short* W8cb = (unsigned short*)(p + o); o += 65536;
  unsigned short* W8wf = (unsigned short*)(p + o); o += 65536;
  unsigned short* W8wb = (unsigned short*)(p + o); o += 65536;
  float* Wpf  = p + o; o += 1024*DWPn;
  float* Wpb  = p + o; o += 1024*DWPn;
  int*   posf = (int*)(p + o); o += 64*512;
  int*   posb = (int*)(p + o); o += 64*512;
  float* sub  = p + o; o += (size_t)64*128*512;   // reused later as hout
  float* hwz  = p + o; o += (size_t)8192*1024;    // reused later as wXf
  float* wq   = p + o; o += (size_t)8192*DWPn;    // reused later as em/emWp/embp
  float* wXb  = p + o; o += (size_t)8192*1024;
  float* wXf  = hwz;            // alias: hwz dead after k_hwelt
  float* hout = sub;            // alias: sub dead after k_wasm
  float* em   = wq;             // alias: wq dead after word-Xih gemm
  float* emWp = wq + 8192*64;
  float* embp = emWp + 64*512;

  float* out  = (float*)d_out;

  hipMemsetAsync(sub, 0, (size_t)64*128*512*sizeof(float), stream);

  k_prep_cw <<<dim3(100,2), 256, 0, stream>>>(ceW, fcWih, fcb, bcWih, bcb, CWf, CWb);
  k_prep_w8 <<<dim3(512,4), 256, 0, stream>>>(fcWhh, bcWhh, wfWhh, wbWhh,
                                              W8cf, W8cb, W8wf, W8wb);
  k_pad     <<<dim3(1024,2), 256, 0, stream>>>(wfWih, wbWih, Wpf, Wpb);
  k_prep_pos<<<dim3(64,2), 64, 0, stream>>>(cmakf, cmakb, posf, posb);

  k_char_lstm<<<32, 1024, 0, stream>>>(cmapsf, cmapsb, CWf, CWb,
                                       (const unsigned char*)W8cf, (const unsigned char*)W8cb,
                                       posf, posb, sub);

  // highway
  k_gemm<<<dim3(64,8,2), 256, 0, stream>>>(sub, 512, 512, 512,
                                           hwWt, hwWg, hwbt, hwbg,
                                           hwz, hwz+512, 1024);
  k_hwelt<<<4096, 256, 0, stream>>>(hwz, sub);

  k_wasm<<<8192, 256, 0, stream>>>(wmap, weW, sub, wq);

  // word input projections
  k_gemm<<<dim3(64,16,2), 256, 0, stream>>>(wq, DWPn, DWPn, DWPn,
                                            Wpf, Wpb, wfb, wbb,
                                            wXf, wXb, 1024);

  k_word_lstm<<<64, 1024, 0, stream>>>(wXf, wXb,
                                       (const unsigned char*)W8wf, (const unsigned char*)W8wb,
                                       hout);

  // em = hout @ emW^T + emb (padded to 64 tags), ld 64
  k_pad_em<<<64, 256, 0, stream>>>(emW, emb, emWp, embp);
  k_gemm<<<dim3(64,1,1), 256, 0, stream>>>(hout, 512, 512, 512,
                                           emWp, emWp, embp, embp,
                                           em, em, 64);

  k_crf<<<8192, 256, 0, stream>>>(em, trans, out);
  k_tail<<<65, 256, 0, stream>>>(tmaps, lengths, tmapc, out + (size_t)20480000);
}